// Round 6
// baseline (514.357 us; speedup 1.0000x reference)
//
#include <hip/hip_runtime.h>
#include <hip/hip_bf16.h>

#define F_NODE 128
#define BINCAP 64

__device__ __forceinline__ float bflo(unsigned int v) {
    return __uint_as_float(v << 16);
}
__device__ __forceinline__ float bfhi(unsigned int v) {
    return __uint_as_float(v & 0xffff0000u);
}
__device__ __forceinline__ unsigned short bfpack(float f) {
    __hip_bfloat16 b = __float2bfloat16(f);
    return *reinterpret_cast<unsigned short*>(&b);
}

// ---------------------------------------------------------------------------
// K0: fold weights on device.
//  Wnt[f][k] = W_node[k][f]                       (32 x 128, transposed)
//  Mt[f2][k] = sum_j Wg[k][j] * Wl_top[j][f2&31]  (64 x 32; f2<32 -> z, else h)
//  cvec[f2]  = sum_j bg[j]*Wl_top[j][f2&31] + bl[f2&31]
//  Wet[f][k] = W_edge[k][f]                       (32 x 32, transposed)
__global__ void k_prep(const float* __restrict__ Wn,
                       const float* __restrict__ Wgz, const float* __restrict__ Wgh,
                       const float* __restrict__ Wlz, const float* __restrict__ Wlh,
                       const float* __restrict__ bgz, const float* __restrict__ bgh,
                       const float* __restrict__ blz, const float* __restrict__ blh,
                       const float* __restrict__ We,
                       float* __restrict__ Wnt, float* __restrict__ Mt,
                       float* __restrict__ cvec, float* __restrict__ Wet) {
    int tid = threadIdx.x;
    for (int j = tid; j < 32 * 128; j += 256) {
        int f = j >> 7, k = j & 127;
        Wnt[j] = Wn[k * 32 + f];
    }
    for (int j = tid; j < 64 * 32; j += 256) {
        int f2 = j >> 5, k = j & 31, f = f2 & 31;
        const float* G = (f2 < 32) ? Wgz : Wgh;
        const float* L = (f2 < 32) ? Wlz : Wlh;
        float s = 0.f;
        for (int q = 0; q < 32; ++q) s += G[k * 32 + q] * L[q * 32 + f];
        Mt[j] = s;
    }
    for (int j = tid; j < 64; j += 256) {
        int f = j & 31;
        const float* L  = (j < 32) ? Wlz : Wlh;
        const float* bg = (j < 32) ? bgz : bgh;
        const float* bl = (j < 32) ? blz : blh;
        float s = bl[f];
        for (int q = 0; q < 32; ++q) s += bg[q] * L[q * 32 + f];
        cvec[j] = s;
    }
    for (int j = tid; j < 32 * 32; j += 256) {
        int f = j >> 5, k = j & 31;
        Wet[j] = We[k * 32 + f];
    }
}

// ---------------------------------------------------------------------------
// FAT kernel, role = blockIdx.x % 7 (5x edge-matmul, 1x bucket-scatter,
// 1x node-encoder). All three roles are independent.
//  MM  : out[e] = relu(ea@We+be).w3 + b0, 2 edges/thread
//  SCAT: phase-A counting sort — append (row | lcol<<20) to bucket[col>>7]
//        (~782 hot frontier lines -> L2 write-combining, unlike old bin fill)
//  ENC : wave-per-node, writes UNSCALED ysb (bf16)
__global__ __launch_bounds__(256) void k_fat3(
        const int* __restrict__ row, const int* __restrict__ col,
        int* __restrict__ bcount, unsigned* __restrict__ buckets, int BCAP,
        const float* __restrict__ ea, const float* __restrict__ Wet,
        const float* __restrict__ be, const float* __restrict__ Wout,
        const float* __restrict__ bout, float* __restrict__ out,
        const float* __restrict__ x, const float* __restrict__ bn,
        const float* __restrict__ Wnt, const float* __restrict__ Mt,
        __hip_bfloat16* __restrict__ ysb,
        int E, int N, int P) {
    __shared__ float sW[1024];
    __shared__ float sb[32], sw3[32];
    __shared__ float sx[4][128];
    __shared__ float sxe[4][32];
    int role = blockIdx.x % 7;
    int sub  = blockIdx.x / 7;
    int tid = threadIdx.x;

    if (role < 5) {
        // ---- edge matmul: 2 edges/thread ----
        for (int j = tid; j < 1024; j += 256) sW[j] = Wet[j];
        if (tid < 32) { sb[tid] = be[tid]; sw3[tid] = Wout[64 + tid]; }
        __syncthreads();
        int chunk = sub * 5 + role;
        int e0 = chunk * 512 + tid, e1 = e0 + 256;
        bool v0 = e0 < E, v1 = e1 < E;
        const float4* ra = (const float4*)(ea + (size_t)(v0 ? e0 : 0) * 32);
        const float4* rb = (const float4*)(ea + (size_t)(v1 ? e1 : 0) * 32);
        float4 er0[8], er1[8];
        #pragma unroll
        for (int r = 0; r < 8; ++r) er0[r] = ra[r];
        #pragma unroll
        for (int r = 0; r < 8; ++r) er1[r] = rb[r];
        float p0 = 0.f, p1 = 0.f;
        #pragma unroll 4
        for (int f = 0; f < 32; ++f) {
            const float4* wf = (const float4*)(sW + f * 32);
            float s00 = 0.f, s01 = 0.f, s10 = 0.f, s11 = 0.f;
            #pragma unroll
            for (int k = 0; k < 8; k += 2) {
                float4 wa = wf[k], wb = wf[k + 1];
                float4 xa = er0[k], xb = er0[k + 1];
                float4 ya = er1[k], yb = er1[k + 1];
                s00 += xa.x*wa.x + xa.y*wa.y + xa.z*wa.z + xa.w*wa.w;
                s01 += xb.x*wb.x + xb.y*wb.y + xb.z*wb.z + xb.w*wb.w;
                s10 += ya.x*wa.x + ya.y*wa.y + ya.z*wa.z + ya.w*wa.w;
                s11 += yb.x*wb.x + yb.y*wb.y + yb.z*wb.z + yb.w*wb.w;
            }
            p0 += fmaxf(sb[f] + s00 + s01, 0.f) * sw3[f];
            p1 += fmaxf(sb[f] + s10 + s11, 0.f) * sw3[f];
        }
        float b0v = bout[0];
        if (v0) out[e0] = p0 + b0v;
        if (v1) out[e1] = p1 + b0v;
        return;
    }

    if (role == 5) {
        // ---- bucket scatter (phase A of counting sort) ----
        int stride = P * 256;
        for (int e = sub * 256 + tid; e < E; e += stride) {
            int r = row[e];
            int c = col[e];
            int b = c >> 7;
            unsigned rec = (unsigned)r | ((unsigned)(c & 127) << 20);
            int p = atomicAdd(&bcount[b], 1);
            if (p < BCAP) buckets[(size_t)b * BCAP + p] = rec;
        }
        return;
    }

    // ---- node encoder: wave-per-node, grid-stride ----
    int w = tid >> 6, l = tid & 63;
    int f = l & 31, kh = l >> 5;

    float4 wreg[16];   // Wnt[f][kh*64 .. kh*64+63]
    const float4* wp = (const float4*)(Wnt + f * 128 + kh * 64);
    #pragma unroll
    for (int r = 0; r < 16; ++r) wreg[r] = wp[r];
    float4 mreg[8];    // Mt[l][0..31]
    const float4* mp = (const float4*)(Mt + l * 32);
    #pragma unroll
    for (int r = 0; r < 8; ++r) mreg[r] = mp[r];
    float bnf = bn[f];

    int stride = P * 4;
    int i = sub * 4 + w;
    float2 xv = make_float2(0.f, 0.f);
    if (i < N) xv = ((const float2*)(x + (size_t)i * F_NODE))[l];

    for (; i < N; i += stride) {
        sx[w][2 * l]     = xv.x;
        sx[w][2 * l + 1] = xv.y;
        int inext = i + stride;
        if (inext < N) xv = ((const float2*)(x + (size_t)inext * F_NODE))[l];

        const float4* sxp = (const float4*)(&sx[w][kh * 64]);
        float a0 = 0.f, a1 = 0.f, a2 = 0.f, a3 = 0.f;
        #pragma unroll
        for (int r = 0; r < 16; r += 4) {
            float4 x0 = sxp[r], x1 = sxp[r + 1], x2 = sxp[r + 2], x3 = sxp[r + 3];
            float4 w0 = wreg[r], w1 = wreg[r + 1], w2 = wreg[r + 2], w3 = wreg[r + 3];
            a0 += x0.x*w0.x + x0.y*w0.y + x0.z*w0.z + x0.w*w0.w;
            a1 += x1.x*w1.x + x1.y*w1.y + x1.z*w1.z + x1.w*w1.w;
            a2 += x2.x*w2.x + x2.y*w2.y + x2.z*w2.z + x2.w*w2.w;
            a3 += x3.x*w3.x + x3.y*w3.y + x3.z*w3.z + x3.w*w3.w;
        }
        float acc = (a0 + a1) + (a2 + a3);
        acc += __shfl_xor(acc, 32);
        acc = fmaxf(acc + bnf, 0.f);
        if (l < 32) sxe[w][l] = acc;

        const float4* sep = (const float4*)(&sxe[w][0]);
        float b0 = 0.f, b1 = 0.f;
        #pragma unroll
        for (int r = 0; r < 8; r += 2) {
            float4 e0 = sep[r], e1 = sep[r + 1];
            float4 m0 = mreg[r], m1 = mreg[r + 1];
            b0 += e0.x*m0.x + e0.y*m0.y + e0.z*m0.z + e0.w*m0.w;
            b1 += e1.x*m1.x + e1.y*m1.y + e1.z*m1.z + e1.w*m1.w;
        }
        ysb[(size_t)i * 64 + l] = __float2bfloat16(b0 + b1);
    }
}

// ---------------------------------------------------------------------------
// Phase B: block per bucket (128 nodes). LDS-bin the bucket's edges,
// stream bin rows out coalesced, write true degrees, and scale this
// bucket's ysb rows by rsqrt(deg+1) in place.
__global__ __launch_bounds__(256) void k_bin(
        const int* __restrict__ bcount, const unsigned* __restrict__ buckets,
        int BCAP, int* __restrict__ bin, int* __restrict__ cursor,
        uint4* __restrict__ ysb4, int N) {
    __shared__ int lbin[128 * 64];   // 32 KB
    __shared__ int hist[128];
    int b = blockIdx.x;
    int tid = threadIdx.x;
    int c0 = b << 7;
    int nloc = N - c0; if (nloc > 128) nloc = 128;

    for (int j = tid; j < 128; j += 256) hist[j] = 0;
    __syncthreads();

    int nb = bcount[b]; if (nb > BCAP) nb = BCAP;
    const unsigned* bp = buckets + (size_t)b * BCAP;
    for (int j = tid; j < nb; j += 256) {
        unsigned v = bp[j];
        int lc = v >> 20;
        int r  = v & 0xFFFFFu;
        int p = atomicAdd(&hist[lc], 1);
        if (p < BINCAP) lbin[(lc << 6) + p] = r;
    }
    __syncthreads();

    // coalesced copy-out of bin rows (garbage beyond cnt is never read)
    const uint4* src = (const uint4*)lbin;
    uint4* dst = (uint4*)(bin + ((size_t)c0 << 6));
    int nq = nloc << 4;               // nloc * 64 ints / 4
    for (int j = tid; j < nq; j += 256) dst[j] = src[j];
    if (tid < nloc) cursor[c0 + tid] = hist[tid];

    // scale ysb rows of this bucket: row = 64 bf16 = 8 uint4
    int nv = nloc << 3;
    for (int j = tid; j < nv; j += 256) {
        int ln = j >> 3;
        float d = rsqrtf((float)hist[ln] + 1.0f);
        size_t idx = (((size_t)(c0 + ln)) << 3) + (j & 7);
        uint4 v = ysb4[idx];
        unsigned in[4] = {v.x, v.y, v.z, v.w};
        unsigned r[4];
        #pragma unroll
        for (int k = 0; k < 4; ++k) {
            unsigned short ul = bfpack(bflo(in[k]) * d);
            unsigned short uh = bfpack(bfhi(in[k]) * d);
            r[k] = (unsigned)ul | ((unsigned)uh << 16);
        }
        ysb4[idx] = make_uint4(r[0], r[1], r[2], r[3]);
    }
}

// ---------------------------------------------------------------------------
// K3: one wave per node; ysb rows PRE-SCALED by dis. Bin row in ONE
// coalesced load; uint2 (4 bf16) per lane, 16 lanes/edge -> 4 edges in flight.
__global__ __launch_bounds__(256) void k_gather(
        const int* __restrict__ cursor, const int* __restrict__ bin,
        const unsigned short* __restrict__ ysb,
        const float* __restrict__ cvec, const float* __restrict__ Wout,
        float* __restrict__ hr, float* __restrict__ hc, int N) {
    int w = threadIdx.x >> 6, l = threadIdx.x & 63;
    int c = blockIdx.x * 4 + w;
    if (c >= N) return;
    int q = l & 15, s = l >> 4;

    int truec = cursor[c];
    float dc = rsqrtf((float)truec + 1.0f);
    int cnt = truec < BINCAP ? truec : BINCAP;
    const int* bp = bin + ((size_t)c << 6);
    int myr = (l < cnt) ? bp[l] : 0;

    float a0 = 0.f, a1 = 0.f, a2 = 0.f, a3 = 0.f;
    uint2 sv = *(const uint2*)(ysb + ((size_t)c << 6) + 4 * q);
    if (s == 0) {
        a0 = bflo(sv.x); a1 = bfhi(sv.x);
        a2 = bflo(sv.y); a3 = bfhi(sv.y);
    }
    for (int j = 0; j < cnt; j += 4) {
        int jj = j + s;
        if (jj < cnt) {
            int r = __shfl(myr, jj);
            uint2 v = *(const uint2*)(ysb + ((size_t)r << 6) + 4 * q);
            a0 += bflo(v.x); a1 += bfhi(v.x);
            a2 += bflo(v.y); a3 += bfhi(v.y);
        }
    }
    a0 += __shfl_xor(a0, 16); a1 += __shfl_xor(a1, 16);
    a2 += __shfl_xor(a2, 16); a3 += __shfl_xor(a3, 16);
    a0 += __shfl_xor(a0, 32); a1 += __shfl_xor(a1, 32);
    a2 += __shfl_xor(a2, 32); a3 += __shfl_xor(a3, 32);

    float4 cv = *(const float4*)(cvec + 4 * q);
    a0 = dc * a0 + cv.x; a1 = dc * a1 + cv.y;
    a2 = dc * a2 + cv.z; a3 = dc * a3 + cv.w;
    float v0, v1, v2, v3;
    if (q < 8) {        // feats 4q..4q+3 in [0,32): Z = sigmoid
        v0 = 1.f / (1.f + __expf(-a0));
        v1 = 1.f / (1.f + __expf(-a1));
        v2 = 1.f / (1.f + __expf(-a2));
        v3 = 1.f / (1.f + __expf(-a3));
    } else {            // feats in [32,64): Ht = tanh
        v0 = tanhf(a0); v1 = tanhf(a1); v2 = tanhf(a2); v3 = tanhf(a3);
    }
    float o0 = __shfl_xor(v0, 8), o1 = __shfl_xor(v1, 8);
    float o2 = __shfl_xor(v2, 8), o3 = __shfl_xor(v3, 8);
    float h0 = (1.f - v0) * o0, h1 = (1.f - v1) * o1;
    float h2 = (1.f - v2) * o2, h3 = (1.f - v3) * o3;
    float4 w0 = *(const float4*)(Wout + 4 * q);
    float4 w1 = *(const float4*)(Wout + 32 + 4 * q);
    float pr = h0*w0.x + h1*w0.y + h2*w0.z + h3*w0.w;
    float pc = h0*w1.x + h1*w1.y + h2*w1.z + h3*w1.w;
    #pragma unroll
    for (int m = 4; m >= 1; m >>= 1) {
        pr += __shfl_xor(pr, m);
        pc += __shfl_xor(pc, m);
    }
    if (l == 0) { hr[c] = pr; hc[c] = pc; }
}

// ---------------------------------------------------------------------------
// K4: out[e] += hr[row[e]] + hc[col[e]]   (hr/hc 400KB each: L2-resident)
__global__ __launch_bounds__(256) void k_edge_add(
        const int* __restrict__ row, const int* __restrict__ col,
        const float* __restrict__ hr, const float* __restrict__ hc,
        float* __restrict__ out, int E) {
    int e = blockIdx.x * 256 + threadIdx.x;
    if (e < E) out[e] += hr[row[e]] + hc[col[e]];
}

// ---------------------------------------------------------------------------
extern "C" void kernel_launch(void* const* d_in, const int* in_sizes, int n_in,
                              void* d_out, int out_size, void* d_ws, size_t ws_size,
                              hipStream_t stream) {
    const float* x    = (const float*)d_in[0];
    const int*   ei   = (const int*)  d_in[1];
    const float* ea   = (const float*)d_in[2];
    const float* Wn   = (const float*)d_in[3];
    const float* bn   = (const float*)d_in[4];
    const float* We   = (const float*)d_in[5];
    const float* be   = (const float*)d_in[6];
    const float* Wgz  = (const float*)d_in[7];
    const float* bgz  = (const float*)d_in[8];
    // d_in[9..10] = Wg_r, bg_r : dead (h0 == 0)
    const float* Wgh  = (const float*)d_in[11];
    const float* bgh  = (const float*)d_in[12];
    const float* Wlz  = (const float*)d_in[13];
    const float* blz  = (const float*)d_in[14];
    // d_in[15..16] = Wl_r, bl_r : dead
    const float* Wlh  = (const float*)d_in[17];
    const float* blh  = (const float*)d_in[18];
    const float* Wout = (const float*)d_in[19];
    const float* bout = (const float*)d_in[20];

    int N = in_sizes[0] / F_NODE;
    int E = in_sizes[1] / 2;
    const int* row = ei;
    const int* col = ei + E;

    int NBUCK = (N + 127) >> 7;
    int BCAP  = E / NBUCK + E / (NBUCK * 4) + 512;   // avg + 25% + slack

    // ws layout (float units):
    // ysb(bf16)[64N]=32N | bin(int)[64N] | buckets(uint)[NBUCK*BCAP]
    // | Wnt[4096] | Mt[2048] | Wet[1024] | cvec[64]
    // | hr[N] | hc[N] | cursor(int)[N] | bcount(int)[NBUCK]
    float* ws    = (float*)d_ws;
    __hip_bfloat16* ysb = (__hip_bfloat16*)ws;
    int*   bin   = (int*)(ws + (size_t)32 * N);
    unsigned* buckets = (unsigned*)(ws + (size_t)96 * N);
    size_t BK = (size_t)NBUCK * BCAP;
    float* Wnt   = ws + (size_t)96 * N + BK;
    float* Mt    = Wnt + 4096;
    float* Wet   = Mt + 2048;
    float* cvec  = Wet + 1024;
    float* hr    = cvec + 64;
    float* hc    = hr + N;
    int*   cursor= (int*)(hc + N);
    int*   bcount= cursor + N;
    float* out   = (float*)d_out;

    hipMemsetAsync(bcount, 0, (size_t)NBUCK * sizeof(int), stream);

    k_prep<<<1, 256, 0, stream>>>(Wn, Wgz, Wgh, Wlz, Wlh, bgz, bgh, blz, blh, We,
                                  Wnt, Mt, cvec, Wet);
    int P = (((E + 511) / 512) + 4) / 5;     // MM periods; 5 MM chunks each
    k_fat3<<<7 * P, 256, 0, stream>>>(row, col, bcount, buckets, BCAP,
                                      ea, Wet, be, Wout, bout, out,
                                      x, bn, Wnt, Mt, ysb, E, N, P);
    k_bin<<<NBUCK, 256, 0, stream>>>(bcount, buckets, BCAP, bin, cursor,
                                     (uint4*)ysb, N);
    k_gather<<<(N + 3) / 4, 256, 0, stream>>>(cursor, bin,
                                              (const unsigned short*)ysb,
                                              cvec, Wout, hr, hc, N);
    k_edge_add<<<(E + 255) / 256, 256, 0, stream>>>(row, col, hr, hc, out, E);
}

// Round 7
// 328.532 us; speedup vs baseline: 1.5656x; 1.5656x over previous
//
#include <hip/hip_runtime.h>
#include <hip/hip_bf16.h>

#define F_NODE 128
#define BINCAP 64
#define ENCB 512

__device__ __forceinline__ float bflo(unsigned int v) {
    return __uint_as_float(v << 16);
}
__device__ __forceinline__ float bfhi(unsigned int v) {
    return __uint_as_float(v & 0xffff0000u);
}
__device__ __forceinline__ unsigned short bfpack(float f) {
    __hip_bfloat16 b = __float2bfloat16(f);
    return *reinterpret_cast<unsigned short*>(&b);
}

// ---------------------------------------------------------------------------
// K0: fold weights on device.
//  M2[k][g]  = sum_j Wg_sel[k][j] * Wl_sel_top[j][g&31]   (32 x 64; g<32 -> z)
//  cvec[g]   = sum_j bg[j]*Wl_top[j][g&31] + bl[g&31]
//  Wet[f][k] = W_edge[k][f]                               (32 x 32, transposed)
__global__ void k_prep(const float* __restrict__ Wgz, const float* __restrict__ Wgh,
                       const float* __restrict__ Wlz, const float* __restrict__ Wlh,
                       const float* __restrict__ bgz, const float* __restrict__ bgh,
                       const float* __restrict__ blz, const float* __restrict__ blh,
                       const float* __restrict__ We,
                       float* __restrict__ M2, float* __restrict__ cvec,
                       float* __restrict__ Wet) {
    int tid = threadIdx.x;
    for (int j = tid; j < 32 * 64; j += 256) {
        int k = j >> 6, g = j & 63, f = g & 31;
        const float* G = (g < 32) ? Wgz : Wgh;
        const float* L = (g < 32) ? Wlz : Wlh;   // top-half rows 0..31 of [64,32]
        float s = 0.f;
        for (int q = 0; q < 32; ++q) s += G[k * 32 + q] * L[q * 32 + f];
        M2[j] = s;
    }
    for (int j = tid; j < 64; j += 256) {
        int f = j & 31;
        const float* L  = (j < 32) ? Wlz : Wlh;
        const float* bg = (j < 32) ? bgz : bgh;
        const float* bl = (j < 32) ? blz : blh;
        float s = bl[f];
        for (int q = 0; q < 32; ++q) s += bg[q] * L[q * 32 + f];
        cvec[j] = s;
    }
    for (int j = tid; j < 32 * 32; j += 256) {
        int f = j >> 5, k = j & 31;
        Wet[j] = We[k * 32 + f];
    }
}

// ---------------------------------------------------------------------------
// FAT kernel. Block roles:
//   bid < ENCB                : node encoder (persistent, grid-stride)
//   bid >= ENCB, (bid-ENCB)&1 : 0 -> bin fill (1 edge/thread, r4-proven)
//                               1 -> edge matmul (1 edge/thread, r4-proven)
// enc keeps VGPR low by reading W_node from LDS in [k][f+pad] layout:
// lanes f=0..31 read consecutive floats (conflict-free b32, 2-way broadcast).
__global__ __launch_bounds__(256) void k_fat(
        const int* __restrict__ row, const int* __restrict__ col,
        int* __restrict__ cursor, int* __restrict__ bin,
        const float* __restrict__ ea, const float* __restrict__ Wet,
        const float* __restrict__ be, const float* __restrict__ Wout,
        const float* __restrict__ bout, float* __restrict__ out,
        const float* __restrict__ x, const float* __restrict__ Wn,
        const float* __restrict__ bn, __hip_bfloat16* __restrict__ ysb,
        int E, int N) {
    __shared__ float smem[5280];   // enc: sWn 4224 | sx 1024 | sbn 32 ; MM: 1088
    int bid = blockIdx.x, tid = threadIdx.x;

    if (bid >= ENCB) {
        int b2 = bid - ENCB;
        if ((b2 & 1) == 0) {
            // ---- bin fill: 1 edge/thread ----
            int e = (b2 >> 1) * 256 + tid;
            if (e < E) {
                int r = row[e];
                int c = col[e];
                int p = atomicAdd(&cursor[c], 1);
                if (p < BINCAP) bin[((size_t)c << 6) + p] = r;
            }
            return;
        }
        // ---- edge matmul: out[e] = relu(ea@We+be).w3 + b0 ----
        float* sW  = smem;
        float* sb  = smem + 1024;
        float* sw3 = smem + 1056;
        for (int j = tid; j < 1024; j += 256) sW[j] = Wet[j];
        if (tid < 32) { sb[tid] = be[tid]; sw3[tid] = Wout[64 + tid]; }
        __syncthreads();
        int e = (b2 >> 1) * 256 + tid;
        if (e >= E) return;
        float b0v = bout[0];
        float4 er[8];
        const float4* erow = (const float4*)(ea + (size_t)e * 32);
        #pragma unroll
        for (int r = 0; r < 8; ++r) er[r] = erow[r];
        float p = 0.f;
        #pragma unroll 4
        for (int f = 0; f < 32; ++f) {
            const float4* wf = (const float4*)(sW + f * 32);
            float a0 = 0.f, a1 = 0.f;
            #pragma unroll
            for (int k = 0; k < 8; k += 2) {
                float4 xa = er[k],     wa = wf[k];
                float4 xb = er[k + 1], wb = wf[k + 1];
                a0 += xa.x*wa.x + xa.y*wa.y + xa.z*wa.z + xa.w*wa.w;
                a1 += xb.x*wb.x + xb.y*wb.y + xb.z*wb.z + xb.w*wb.w;
            }
            p += fmaxf(sb[f] + a0 + a1, 0.f) * sw3[f];
        }
        out[e] = p + b0v;
        return;
    }

    // ---- node encoder: 2 nodes per wave (lane half = node), grid-stride ----
    //   xe = relu(x @ Wn + bn)  [32];  ysb[node][f] = bf16(xe[f])  (unscaled)
    float* sWn = smem;          // [128][33]
    float* sx  = smem + 4224;   // [4 waves][2 nodes][128]
    float* sbn = smem + 5248;   // [32]
    for (int j = tid; j < 4096; j += 256) {
        int k = j >> 5, f = j & 31;
        sWn[k * 33 + f] = Wn[j];
    }
    if (tid < 32) sbn[tid] = bn[tid];
    __syncthreads();

    int w = tid >> 6, l = tid & 63;
    int f = l & 31, h2 = l >> 5;
    float* sxw = sx + w * 256 + h2 * 128;

    int NP = (N + 1) >> 1;
    int stride = ENCB * 4;
    int p = bid * 4 + w;
    float4 xv = make_float4(0.f, 0.f, 0.f, 0.f);
    int n0 = 2 * p + h2;
    if (n0 < N) xv = ((const float4*)(x + (size_t)n0 * F_NODE))[f];

    for (; p < NP; p += stride) {
        ((float4*)sxw)[f] = xv;     // wave-private: no barrier needed
        int pn = p + stride;
        int nn = 2 * pn + h2;
        if (nn < N) xv = ((const float4*)(x + (size_t)nn * F_NODE))[f];

        float acc = sbn[f];
        #pragma unroll 8
        for (int k = 0; k < 128; ++k)
            acc += sxw[k] * sWn[k * 33 + f];

        int node = 2 * p + h2;
        if (node < N)
            ysb[(size_t)node * 32 + f] = __float2bfloat16(fmaxf(acc, 0.f));
    }
}

// ---------------------------------------------------------------------------
// K2: in-place scale  ysb[i][:] *= rsqrt(deg_i + 1)  (row = 32 bf16 = 4 uint4)
__global__ __launch_bounds__(256) void k_scale(
        uint4* __restrict__ ysb4, const int* __restrict__ cursor, int N) {
    int t = blockIdx.x * 256 + threadIdx.x;
    if (t >= N * 4) return;
    float d = rsqrtf((float)cursor[t >> 2] + 1.0f);
    uint4 v = ysb4[t];
    unsigned in[4] = {v.x, v.y, v.z, v.w};
    unsigned r[4];
    #pragma unroll
    for (int j = 0; j < 4; ++j) {
        unsigned short ul = bfpack(bflo(in[j]) * d);
        unsigned short uh = bfpack(bfhi(in[j]) * d);
        r[j] = (unsigned)ul | ((unsigned)uh << 16);
    }
    ysb4[t] = make_uint4(r[0], r[1], r[2], r[3]);
}

// ---------------------------------------------------------------------------
// K3: one wave per node. ysb rows PRE-SCALED 32-dim (64B = 1 line per row).
// Lane (q=l&7, s=l>>3): uint2 = 4 bf16 per lane, 8 lanes/edge -> 8 edges in
// flight. After reduce: S[32] distributed 4-per-q-lane; epilogue matvec
// a[g] = dc*(S@M2)[g] + cvec[g], Z/Ht split, hr/hc scalars.
__global__ __launch_bounds__(256) void k_gather(
        const int* __restrict__ cursor, const int* __restrict__ bin,
        const unsigned short* __restrict__ ysb,
        const float* __restrict__ M2, const float* __restrict__ cvec,
        const float* __restrict__ Wout,
        float* __restrict__ hr, float* __restrict__ hc, int N) {
    __shared__ float sM[2048];
    __shared__ float scv[64], sw0[32], sw1[32];
    int tid = threadIdx.x;
    for (int j = tid; j < 2048; j += 256) sM[j] = M2[j];
    if (tid < 64) scv[tid] = cvec[tid];
    if (tid < 32) { sw0[tid] = Wout[tid]; sw1[tid] = Wout[32 + tid]; }
    __syncthreads();

    int w = tid >> 6, l = tid & 63;
    int c = blockIdx.x * 4 + w;
    if (c >= N) return;
    int q = l & 7, s = l >> 3;

    int truec = cursor[c];
    float dc = rsqrtf((float)truec + 1.0f);
    int cnt = truec < BINCAP ? truec : BINCAP;
    const int* bp = bin + ((size_t)c << 6);
    int myr = (l < cnt) ? bp[l] : 0;

    float a0 = 0.f, a1 = 0.f, a2 = 0.f, a3 = 0.f;
    uint2 sv = *(const uint2*)(ysb + (size_t)c * 32 + 4 * q);
    if (s == 0) {
        a0 = bflo(sv.x); a1 = bfhi(sv.x);
        a2 = bflo(sv.y); a3 = bfhi(sv.y);
    }
    for (int j = 0; j < cnt; j += 8) {
        int jj = j + s;
        if (jj < cnt) {
            int r = __shfl(myr, jj);
            uint2 v = *(const uint2*)(ysb + (size_t)r * 32 + 4 * q);
            a0 += bflo(v.x); a1 += bfhi(v.x);
            a2 += bflo(v.y); a3 += bfhi(v.y);
        }
    }
    a0 += __shfl_xor(a0, 8);  a1 += __shfl_xor(a1, 8);
    a2 += __shfl_xor(a2, 8);  a3 += __shfl_xor(a3, 8);
    a0 += __shfl_xor(a0, 16); a1 += __shfl_xor(a1, 16);
    a2 += __shfl_xor(a2, 16); a3 += __shfl_xor(a3, 16);
    a0 += __shfl_xor(a0, 32); a1 += __shfl_xor(a1, 32);
    a2 += __shfl_xor(a2, 32); a3 += __shfl_xor(a3, 32);
    // every lane now holds S[4q..4q+3]

    // matvec: output g = l
    float acc = 0.f;
    #pragma unroll
    for (int kq = 0; kq < 8; ++kq) {
        float s0 = __shfl(a0, kq), s1 = __shfl(a1, kq);
        float s2 = __shfl(a2, kq), s3 = __shfl(a3, kq);
        int k = 4 * kq;
        acc += s0 * sM[k * 64 + l]       + s1 * sM[(k + 1) * 64 + l]
             + s2 * sM[(k + 2) * 64 + l] + s3 * sM[(k + 3) * 64 + l];
    }
    float a = dc * acc + scv[l];
    float v = (l < 32) ? (1.f / (1.f + __expf(-a))) : tanhf(a);
    float o = __shfl_xor(v, 32);
    float h = (1.f - v) * o;             // valid on lanes l<32
    float pr = h * sw0[l & 31];
    float pc = h * sw1[l & 31];
    #pragma unroll
    for (int m = 16; m >= 1; m >>= 1) {
        pr += __shfl_xor(pr, m);
        pc += __shfl_xor(pc, m);
    }
    if (l == 0) { hr[c] = pr; hc[c] = pc; }
}

// ---------------------------------------------------------------------------
// K4: out[e] += hr[row[e]] + hc[col[e]]   (hr/hc 400KB each: L2-resident)
__global__ __launch_bounds__(256) void k_edge_add(
        const int* __restrict__ row, const int* __restrict__ col,
        const float* __restrict__ hr, const float* __restrict__ hc,
        float* __restrict__ out, int E) {
    int e = blockIdx.x * 256 + threadIdx.x;
    if (e < E) out[e] += hr[row[e]] + hc[col[e]];
}

// ---------------------------------------------------------------------------
extern "C" void kernel_launch(void* const* d_in, const int* in_sizes, int n_in,
                              void* d_out, int out_size, void* d_ws, size_t ws_size,
                              hipStream_t stream) {
    const float* x    = (const float*)d_in[0];
    const int*   ei   = (const int*)  d_in[1];
    const float* ea   = (const float*)d_in[2];
    const float* Wn   = (const float*)d_in[3];
    const float* bn   = (const float*)d_in[4];
    const float* We   = (const float*)d_in[5];
    const float* be   = (const float*)d_in[6];
    const float* Wgz  = (const float*)d_in[7];
    const float* bgz  = (const float*)d_in[8];
    // d_in[9..10] = Wg_r, bg_r : dead (h0 == 0)
    const float* Wgh  = (const float*)d_in[11];
    const float* bgh  = (const float*)d_in[12];
    const float* Wlz  = (const float*)d_in[13];
    const float* blz  = (const float*)d_in[14];
    // d_in[15..16] = Wl_r, bl_r : dead
    const float* Wlh  = (const float*)d_in[17];
    const float* blh  = (const float*)d_in[18];
    const float* Wout = (const float*)d_in[19];
    const float* bout = (const float*)d_in[20];

    int N = in_sizes[0] / F_NODE;
    int E = in_sizes[1] / 2;
    const int* row = ei;
    const int* col = ei + E;

    // ws layout (float units):
    // ysb(bf16)[32N]=16N | bin(int)[64N] | M2[2048] | Wet[1024] | cvec[64]
    // | hr[N] | hc[N] | cursor(int)[N]
    float* ws    = (float*)d_ws;
    __hip_bfloat16* ysb = (__hip_bfloat16*)ws;
    int*   bin   = (int*)(ws + (size_t)16 * N);
    float* M2    = ws + (size_t)80 * N;
    float* Wet   = M2 + 2048;
    float* cvec  = Wet + 1024;
    float* hr    = cvec + 64;
    float* hc    = hr + N;
    int*   cursor= (int*)(hc + N);
    float* out   = (float*)d_out;

    hipMemsetAsync(cursor, 0, (size_t)N * sizeof(int), stream);

    k_prep<<<1, 256, 0, stream>>>(Wgz, Wgh, Wlz, Wlh, bgz, bgh, blz, blh, We,
                                  M2, cvec, Wet);
    int eb = (E + 255) / 256;
    k_fat<<<ENCB + 2 * eb, 256, 0, stream>>>(row, col, cursor, bin,
                                             ea, Wet, be, Wout, bout, out,
                                             x, Wn, bn, ysb, E, N);
    k_scale<<<(4 * N + 255) / 256, 256, 0, stream>>>((uint4*)ysb, cursor, N);
    k_gather<<<(N + 3) / 4, 256, 0, stream>>>(cursor, bin,
                                              (const unsigned short*)ysb,
                                              M2, cvec, Wout, hr, hc, N);
    k_edge_add<<<eb, 256, 0, stream>>>(row, col, hr, hc, out, E);
}